// Round 15
// baseline (161.326 us; speedup 1.0000x reference)
//
#include <hip/hip_runtime.h>

// ---------------- problem constants (match reference) ----------------
constexpr int F_IN = 256;
constexpr int H1 = 4, D1 = 32, F1 = H1 * D1;   // 128
constexpr int H2 = 1, D2 = 32, F2 = H2 * D2;   // 32
constexpr float NEG = 0.2f;

// CSR build params
constexpr int BW = 128;          // nodes per bucket (pow2)
constexpr int NBUK_MAX = 512;    // >= ceil(N/BW) = 391
constexpr int CB = 256;          // coarse blocks (one per CU)

typedef short short8 __attribute__((ext_vector_type(8)));
typedef float f32x4 __attribute__((ext_vector_type(4)));

__device__ inline float bf2f(unsigned short u) {
    unsigned int x = ((unsigned int)u) << 16;
    return __builtin_bit_cast(float, x);
}
__device__ inline unsigned short f2bf(float f) {
    __bf16 h = (__bf16)f;                      // RNE
    return __builtin_bit_cast(unsigned short, h);
}

// ---------------- CSR build: bucketed two-level counting sort (4 kernels) ----------------
__global__ __launch_bounds__(256) void chist(const int* __restrict__ dst,
                                             unsigned int* __restrict__ HcT,
                                             int E, int nbuk) {
    __shared__ unsigned int h[NBUK_MAX];
    int tid = threadIdx.x;
    for (int i = tid; i < nbuk; i += 256) h[i] = 0;
    __syncthreads();
    int epb = (E + CB - 1) / CB;
    int e0 = blockIdx.x * epb, e1 = min(e0 + epb, E);
    for (int e = e0 + tid; e < e1; e += 256)
        atomicAdd(&h[((unsigned)dst[e]) >> 7], 1u);
    __syncthreads();
    for (int i = tid; i < nbuk; i += 256) HcT[(size_t)i * CB + blockIdx.x] = h[i];
}

__global__ __launch_bounds__(512) void bscan(const unsigned int* __restrict__ HcT,
                                             unsigned int* __restrict__ Bb,
                                             unsigned int* __restrict__ S, int nbuk) {
    __shared__ unsigned int tot[NBUK_MAX];
    int t = threadIdx.x;
    unsigned int run = 0;
    if (t < nbuk) {
        const uint4* row = (const uint4*)(HcT + (size_t)t * CB);
#pragma unroll 8
        for (int b4 = 0; b4 < CB / 4; ++b4) {
            uint4 v = row[b4];
            int b = b4 * 4;
            Bb[(size_t)(b + 0) * nbuk + t] = run; run += v.x;
            Bb[(size_t)(b + 1) * nbuk + t] = run; run += v.y;
            Bb[(size_t)(b + 2) * nbuk + t] = run; run += v.z;
            Bb[(size_t)(b + 3) * nbuk + t] = run; run += v.w;
        }
    }
    tot[t] = (t < nbuk) ? run : 0;
    __syncthreads();
    for (int o = 1; o < NBUK_MAX; o <<= 1) {
        unsigned int v = (t >= o) ? tot[t - o] : 0;
        __syncthreads();
        tot[t] += v;
        __syncthreads();
    }
    if (t < nbuk) S[t] = tot[t] - run;          // exclusive
    if (t == nbuk - 1) S[nbuk] = tot[t];        // == E
}

__global__ __launch_bounds__(256) void cscat(const int* __restrict__ src,
                                             const int* __restrict__ dst,
                                             const unsigned int* __restrict__ Bb,
                                             const unsigned int* __restrict__ S,
                                             unsigned int* __restrict__ pairs, int E, int nbuk) {
    __shared__ unsigned int h[NBUK_MAX];
    int tid = threadIdx.x;
    for (int i = tid; i < nbuk; i += 256)
        h[i] = S[i] + Bb[(size_t)blockIdx.x * nbuk + i];
    __syncthreads();
    int epb = (E + CB - 1) / CB;
    int e0 = blockIdx.x * epb, e1 = min(e0 + epb, E);
    for (int e = e0 + tid; e < e1; e += 256) {
        int d = dst[e];
        int k = ((unsigned)d) >> 7;
        unsigned int p = atomicAdd(&h[k], 1u);
        pairs[p] = ((unsigned int)(d & 127) << 17) | (unsigned int)src[e];
    }
}

__global__ __launch_bounds__(256) void fscat(const unsigned int* __restrict__ pairs,
                                             const unsigned int* __restrict__ S,
                                             int* __restrict__ off, int* __restrict__ csr,
                                             int n, int E) {
    int k = blockIdx.x;
    int tid = threadIdx.x;
    unsigned int s0 = S[k], s1 = S[k + 1];
    __shared__ unsigned int cnt[BW];
    __shared__ unsigned int ex[BW];
    if (tid < BW) cnt[tid] = 0;
    __syncthreads();
    for (unsigned int i = s0 + tid; i < s1; i += 256)
        atomicAdd(&cnt[pairs[i] >> 17], 1u);
    __syncthreads();
    unsigned int orig = (tid < BW) ? cnt[tid] : 0;
    if (tid < BW) ex[tid] = orig;
    __syncthreads();
    for (int o = 1; o < BW; o <<= 1) {
        unsigned int v = (tid < BW && tid >= (unsigned)o) ? ex[tid - o] : 0;
        __syncthreads();
        if (tid < BW) ex[tid] += v;
        __syncthreads();
    }
    if (tid < BW) {
        ex[tid] -= orig;                        // exclusive within bucket
        int node = k * BW + tid;
        if (node < n) off[node] = (int)(s0 + ex[tid]);
    }
    if (tid < BW) cnt[tid] = 0;
    __syncthreads();
    for (unsigned int i = s0 + tid; i < s1; i += 256) {
        unsigned int pr = pairs[i];
        int loc = pr >> 17;
        unsigned int r = atomicAdd(&cnt[loc], 1u);
        csr[s0 + ex[loc] + r] = (int)(pr & 0x1FFFFu);
    }
    if (k == 0 && tid == 0) off[n] = E;
}

// ---------------- prep: W split+swizzle AND X swizzle in one launch ----------------
__device__ inline void wsplit_one(const float* W, unsigned short* Wh, unsigned short* Wl,
                                  int idx, int C) {
    int j    = idx & 7;
    int lane = (idx >> 3) & 63;
    int t    = idx >> 9;
    int FC   = C >> 4;
    int fc   = t % FC, ks = t / FC;
    int k = ks * 32 + (lane >> 4) * 8 + j;
    int c = fc * 16 + (lane & 15);
    float v = W[(size_t)k * C + c];
    __bf16 h = (__bf16)v;
    float hv = (float)h;
    __bf16 lo = (__bf16)(v - hv);
    Wh[idx] = __builtin_bit_cast(unsigned short, h);
    Wl[idx] = __builtin_bit_cast(unsigned short, lo);
}

constexpr int WBLK = (F_IN * F1 + F1 * F2) / 256;   // 144

__global__ __launch_bounds__(256) void prep_kernel(
    const float* __restrict__ W1, unsigned short* __restrict__ W1h,
    unsigned short* __restrict__ W1l,
    const float* __restrict__ W2, unsigned short* __restrict__ W2h,
    unsigned short* __restrict__ W2l,
    const float* __restrict__ x, unsigned short* __restrict__ xb,
    int n, int nrow_pad)
{
    int bid = blockIdx.x;
    if (bid < WBLK) {
        int idx = bid * 256 + threadIdx.x;
        constexpr int N1 = F_IN * F1;
        if (idx < N1) wsplit_one(W1, W1h, W1l, idx, F1);
        else wsplit_one(W2, W2h, W2l, idx - N1, F2);
        return;
    }
    // X swizzle: x[N][256] f32 -> bf16 A-fragments
    int tid = threadIdx.x;
    int lane = tid & 63;
    int wid = tid >> 6;
    int half = lane >> 5;
    int l32 = lane & 31;
    int ks = l32 >> 2;
    int khi = l32 & 3;
    int row = (bid - WBLK) * 8 + wid * 2 + half;
    if (row >= nrow_pad) return;
    float v[8];
    if (row < n) {
        const float* p = x + (size_t)row * F_IN + ks * 32 + khi * 8;
        float4 a = *(const float4*)p;
        float4 b = *(const float4*)(p + 4);
        v[0] = a.x; v[1] = a.y; v[2] = a.z; v[3] = a.w;
        v[4] = b.x; v[5] = b.y; v[6] = b.z; v[7] = b.w;
    } else {
#pragma unroll
        for (int j = 0; j < 8; ++j) v[j] = 0.f;
    }
    short8 s;
#pragma unroll
    for (int j = 0; j < 8; ++j) s[j] = (short)f2bf(v[j]);
    int frag16 = row >> 4;
    int fragLane = (row & 15) | (khi << 4);
    *(short8*)(xb + (((size_t)frag16 * 8 + ks) * 64 + fragLane) * 8) = s;
}

// ---------------- Layer-1 GEMM: no LDS, both operands pre-swizzled, fused el/er ----------
constexpr int BM1 = 64;
__global__ __launch_bounds__(256) void gemm1_mfma(
    const unsigned short* __restrict__ Xb,
    const unsigned short* __restrict__ Wh,
    const unsigned short* __restrict__ Wl,
    const float* __restrict__ alv, const float* __restrict__ arv,
    unsigned short* __restrict__ outb,
    float* __restrict__ el, float* __restrict__ er, int n)
{
    const int tid  = threadIdx.x;
    const int lane = tid & 63;
    const int wid  = tid >> 6;
    const int wrow = (wid >> 1) * 32;           // 0 or 32
    const int wcol = (wid & 1) * 64;            // 0 or 64
    const int wc16 = wcol >> 4;
    const int row0 = blockIdx.x * BM1;
    const int l16  = lane & 15;
    const int khi  = lane >> 4;                 // 0..3
    const int fbase = blockIdx.x * 4 + (wid >> 1) * 2;  // frag16 index for mi=0

    f32x4 acc[2][4];
#pragma unroll
    for (int mi = 0; mi < 2; ++mi)
#pragma unroll
        for (int ni = 0; ni < 4; ++ni) acc[mi][ni] = f32x4{0.f, 0.f, 0.f, 0.f};

#pragma unroll
    for (int ks = 0; ks < 8; ++ks) {
        short8 ah[2];
#pragma unroll
        for (int mi = 0; mi < 2; ++mi)
            ah[mi] = *(const short8*)(Xb + (((size_t)(fbase + mi) * 8 + ks) * 64 + lane) * 8);

        short8 bh[4], bl[4];
#pragma unroll
        for (int ni = 0; ni < 4; ++ni) {
            int base = ((ks * 8 + wc16 + ni) * 64 + lane) * 8;
            bh[ni] = *(const short8*)(Wh + base);
            bl[ni] = *(const short8*)(Wl + base);
        }

#pragma unroll
        for (int mi = 0; mi < 2; ++mi)
#pragma unroll
            for (int ni = 0; ni < 4; ++ni) {
                acc[mi][ni] = __builtin_amdgcn_mfma_f32_16x16x32_bf16(ah[mi], bl[ni], acc[mi][ni], 0, 0, 0);
                acc[mi][ni] = __builtin_amdgcn_mfma_f32_16x16x32_bf16(ah[mi], bh[ni], acc[mi][ni], 0, 0, 0);
            }
    }

    // ---- epilogue: bf16 feat store + fused el/er ----
    const int hh0 = wcol >> 5;                  // first head this wave covers (0 or 2)
    float alr[2][2], arr[2][2];
#pragma unroll
    for (int t = 0; t < 2; ++t) {
        int head = hh0 + t;
        alr[t][0] = alv[head * 32 + l16];
        alr[t][1] = alv[head * 32 + 16 + l16];
        arr[t][0] = arv[head * 32 + l16];
        arr[t][1] = arv[head * 32 + 16 + l16];
    }

#pragma unroll
    for (int mi = 0; mi < 2; ++mi) {
        int rbase = row0 + wrow + mi * 16 + khi * 4;
#pragma unroll
        for (int rr = 0; rr < 4; ++rr) {
            int row = rbase + rr;
            bool ok = row < n;
            if (ok) {
#pragma unroll
                for (int ni = 0; ni < 4; ++ni)
                    outb[(size_t)row * F1 + wcol + ni * 16 + l16] = f2bf(acc[mi][ni][rr]);
            }
#pragma unroll
            for (int t = 0; t < 2; ++t) {
                float pel = acc[mi][2 * t][rr] * alr[t][0] + acc[mi][2 * t + 1][rr] * alr[t][1];
                float per = acc[mi][2 * t][rr] * arr[t][0] + acc[mi][2 * t + 1][rr] * arr[t][1];
#pragma unroll
                for (int o = 1; o < 16; o <<= 1) {
                    pel += __shfl_xor(pel, o);
                    per += __shfl_xor(per, o);
                }
                if (ok && l16 == 0) {
                    el[(size_t)row * H1 + hh0 + t] = pel;
                    er[(size_t)row * H1 + hh0 + t] = per;
                }
            }
        }
    }
}

// ---------------- Layer-2 GEMM: LDS-staged X + swizzled W + fused el/er; bf16 out ----------
constexpr int BM2 = 64;
__global__ __launch_bounds__(256) void gemm2_mfma(
    const float* __restrict__ X,
    const unsigned short* __restrict__ Wh,
    const unsigned short* __restrict__ Wl,
    const float* __restrict__ alv, const float* __restrict__ arv,
    unsigned short* __restrict__ outb,
    float* __restrict__ el, float* __restrict__ er, int n)
{
    __shared__ float xs[32 * BM2 * 4];          // 32 KB
    const int tid  = threadIdx.x;
    const int lane = tid & 63;
    const int wid  = tid >> 6;
    const int wrow = wid * 16;
    const int row0 = blockIdx.x * BM2;
    const int l16  = lane & 15;
    const int khi  = lane >> 4;

    {
        int gr = row0 + lane;
        gr = gr < n ? gr : (n - 1);
        const float* rowp = X + (size_t)gr * F1;
#pragma unroll
        for (int i = 0; i < 8; ++i) {
            int kc = wid * 8 + i;
            const float* srcp = rowp + kc * 4;
            float* dstf = &xs[kc * BM2 * 4];
            __builtin_amdgcn_global_load_lds(
                (const __attribute__((address_space(1))) unsigned int*)srcp,
                (__attribute__((address_space(3))) unsigned int*)dstf,
                16, 0, 0);
        }
    }
    asm volatile("s_waitcnt vmcnt(0)" ::: "memory");
    __syncthreads();

    f32x4 acc[2];
#pragma unroll
    for (int ni = 0; ni < 2; ++ni) acc[ni] = f32x4{0.f, 0.f, 0.f, 0.f};

    const int rt = wrow + l16;

#pragma unroll
    for (int ks = 0; ks < 4; ++ks) {
        const int kc = ks * 8 + khi * 2;

        short8 bh[2], bl[2];
#pragma unroll
        for (int ni = 0; ni < 2; ++ni) {
            int base = ((ks * 2 + ni) * 64 + lane) * 8;
            bh[ni] = *(const short8*)(Wh + base);
            bl[ni] = *(const short8*)(Wl + base);
        }

        float4 xa0 = *(const float4*)&xs[(kc + 0) * BM2 * 4 + rt * 4];
        float4 xa1 = *(const float4*)&xs[(kc + 1) * BM2 * 4 + rt * 4];
        float v[8] = {xa0.x, xa0.y, xa0.z, xa0.w, xa1.x, xa1.y, xa1.z, xa1.w};
        short8 ah, al8;
#pragma unroll
        for (int j = 0; j < 8; ++j) {
            __bf16 h = (__bf16)v[j];
            float hv = (float)h;
            __bf16 lo = (__bf16)(v[j] - hv);
            ah[j] = __builtin_bit_cast(short, h);
            al8[j] = __builtin_bit_cast(short, lo);
        }

#pragma unroll
        for (int ni = 0; ni < 2; ++ni) {
            acc[ni] = __builtin_amdgcn_mfma_f32_16x16x32_bf16(al8, bh[ni], acc[ni], 0, 0, 0);
            acc[ni] = __builtin_amdgcn_mfma_f32_16x16x32_bf16(ah, bl[ni], acc[ni], 0, 0, 0);
            acc[ni] = __builtin_amdgcn_mfma_f32_16x16x32_bf16(ah, bh[ni], acc[ni], 0, 0, 0);
        }
    }

    float al0 = alv[l16], al1c = alv[16 + l16];
    float ar0 = arv[l16], ar1c = arv[16 + l16];

    int rbase = row0 + wrow + khi * 4;
#pragma unroll
    for (int rr = 0; rr < 4; ++rr) {
        int row = rbase + rr;
        bool ok = row < n;
        if (ok) {
#pragma unroll
            for (int ni = 0; ni < 2; ++ni)
                outb[(size_t)row * F2 + ni * 16 + l16] = f2bf(acc[ni][rr]);
        }
        float pel = acc[0][rr] * al0 + acc[1][rr] * al1c;
        float per = acc[0][rr] * ar0 + acc[1][rr] * ar1c;
#pragma unroll
        for (int o = 1; o < 16; o <<= 1) {
            pel += __shfl_xor(pel, o);
            per += __shfl_xor(per, o);
        }
        if (ok && l16 == 0) {
            el[row] = pel;
            er[row] = per;
        }
    }
}

// ---------------- Aggregation layer 1: bf16 gather, 16 edges in flight ----------------
__global__ __launch_bounds__(256) void agg1_kernel(
    const int* __restrict__ off, const int* __restrict__ csr_src,
    const unsigned short* __restrict__ featb, const float* __restrict__ el,
    const float* __restrict__ er, const float* __restrict__ b,
    float* __restrict__ out, int n)
{
    int wid = (blockIdx.x * 256 + threadIdx.x) >> 6;   // node
    int lane = threadIdx.x & 63;
    if (wid >= n) return;
    int c0 = (lane & 31) * 4;
    int h = (lane & 31) >> 3;
    int half = lane >> 5;
    float erv = er[(size_t)wid * H1 + h];
    float sw = 0.f;
    float4 acc = {0.f, 0.f, 0.f, 0.f};
    int jb = off[wid], je = off[wid + 1];
    int j = jb + half;
    // 8 edges per half in flight (16/wave)
    for (; j + 14 < je; j += 16) {
        int s[8];
#pragma unroll
        for (int q = 0; q < 8; ++q) s[q] = csr_src[j + 2 * q];
        ushort4 u[8];
#pragma unroll
        for (int q = 0; q < 8; ++q)
            u[q] = *(const ushort4*)(featb + (size_t)s[q] * F1 + c0);
        float t[8];
#pragma unroll
        for (int q = 0; q < 8; ++q) t[q] = el[(size_t)s[q] * H1 + h] + erv;
#pragma unroll
        for (int q = 0; q < 8; ++q) {
            float tt = t[q] > 0.f ? t[q] : NEG * t[q];
            float wq = __expf(tt);
            sw += wq;
            acc.x = fmaf(wq, bf2f(u[q].x), acc.x);
            acc.y = fmaf(wq, bf2f(u[q].y), acc.y);
            acc.z = fmaf(wq, bf2f(u[q].z), acc.z);
            acc.w = fmaf(wq, bf2f(u[q].w), acc.w);
        }
    }
    for (; j < je; j += 2) {
        int s = csr_src[j];
        ushort4 u = *(const ushort4*)(featb + (size_t)s * F1 + c0);
        float t = el[(size_t)s * H1 + h] + erv;
        t = t > 0.f ? t : NEG * t;
        float w = __expf(t);
        sw += w;
        acc.x = fmaf(w, bf2f(u.x), acc.x);
        acc.y = fmaf(w, bf2f(u.y), acc.y);
        acc.z = fmaf(w, bf2f(u.z), acc.z);
        acc.w = fmaf(w, bf2f(u.w), acc.w);
    }
    acc.x += __shfl_xor(acc.x, 32);
    acc.y += __shfl_xor(acc.y, 32);
    acc.z += __shfl_xor(acc.z, 32);
    acc.w += __shfl_xor(acc.w, 32);
    sw    += __shfl_xor(sw, 32);
    if (half == 0) {
        float inv = 1.f / fmaxf(sw, 1e-16f);
        float4 bb = *(const float4*)(b + c0);
        float4 t = {acc.x * inv + bb.x, acc.y * inv + bb.y,
                    acc.z * inv + bb.z, acc.w * inv + bb.w};
        *(float4*)(out + (size_t)wid * F1 + c0) = t;
    }
}

// ---------------- Aggregation layer 2: bf16 gather, 32 edges in flight ----------------
__global__ __launch_bounds__(256) void agg2_kernel(
    const int* __restrict__ off, const int* __restrict__ csr_src,
    const unsigned short* __restrict__ featb, const float* __restrict__ el,
    const float* __restrict__ er, const float* __restrict__ b,
    float* __restrict__ out, int n)
{
    int wid = (blockIdx.x * 256 + threadIdx.x) >> 6;   // node
    int lane = threadIdx.x & 63;
    if (wid >= n) return;
    int c0 = (lane & 7) * 4;
    int grp = lane >> 3;
    float erv = er[wid];
    float sw = 0.f;
    float4 acc = {0.f, 0.f, 0.f, 0.f};
    int jb = off[wid], je = off[wid + 1];
    int j = jb + grp;
    for (; j + 24 < je; j += 32) {
        int s[4];
#pragma unroll
        for (int q = 0; q < 4; ++q) s[q] = csr_src[j + 8 * q];
        ushort4 u[4];
#pragma unroll
        for (int q = 0; q < 4; ++q)
            u[q] = *(const ushort4*)(featb + (size_t)s[q] * F2 + c0);
        float t[4];
#pragma unroll
        for (int q = 0; q < 4; ++q) t[q] = el[s[q]] + erv;
#pragma unroll
        for (int q = 0; q < 4; ++q) {
            float tt = t[q] > 0.f ? t[q] : NEG * t[q];
            float wq = __expf(tt);
            sw += wq;
            acc.x = fmaf(wq, bf2f(u[q].x), acc.x);
            acc.y = fmaf(wq, bf2f(u[q].y), acc.y);
            acc.z = fmaf(wq, bf2f(u[q].z), acc.z);
            acc.w = fmaf(wq, bf2f(u[q].w), acc.w);
        }
    }
    for (; j < je; j += 8) {
        int s = csr_src[j];
        ushort4 u = *(const ushort4*)(featb + (size_t)s * F2 + c0);
        float t = el[s] + erv;
        t = t > 0.f ? t : NEG * t;
        float w = __expf(t);
        sw += w;
        acc.x = fmaf(w, bf2f(u.x), acc.x);
        acc.y = fmaf(w, bf2f(u.y), acc.y);
        acc.z = fmaf(w, bf2f(u.z), acc.z);
        acc.w = fmaf(w, bf2f(u.w), acc.w);
    }
#pragma unroll
    for (int o = 8; o < 64; o <<= 1) {
        acc.x += __shfl_xor(acc.x, o);
        acc.y += __shfl_xor(acc.y, o);
        acc.z += __shfl_xor(acc.z, o);
        acc.w += __shfl_xor(acc.w, o);
        sw    += __shfl_xor(sw, o);
    }
    if (lane < 8) {
        float inv = 1.f / fmaxf(sw, 1e-16f);
        float4 bb = *(const float4*)(b + c0);
        float4 t = {acc.x * inv + bb.x, acc.y * inv + bb.y,
                    acc.z * inv + bb.z, acc.w * inv + bb.w};
        *(float4*)(out + (size_t)wid * F2 + c0) = t;
    }
}

// ---------------- launch ----------------
extern "C" void kernel_launch(void* const* d_in, const int* in_sizes, int n_in,
                              void* d_out, int out_size, void* d_ws, size_t ws_size,
                              hipStream_t stream) {
    const float* x   = (const float*)d_in[0];
    const float* W1  = (const float*)d_in[1];
    const float* al1 = (const float*)d_in[2];
    const float* ar1 = (const float*)d_in[3];
    const float* b1  = (const float*)d_in[4];
    const float* W2  = (const float*)d_in[5];
    const float* al2 = (const float*)d_in[6];
    const float* ar2 = (const float*)d_in[7];
    const float* b2  = (const float*)d_in[8];
    const int*   src = (const int*)d_in[9];
    const int*   dst = (const int*)d_in[10];

    const int N = in_sizes[0] / F_IN;
    const int E = in_sizes[9];
    const int NBUK = (N + BW - 1) / BW;          // 391
    const int NBLK1 = (N + BM1 - 1) / BM1;       // 782
    const int NROWP = NBLK1 * BM1;               // padded rows (50048)

    // workspace layout (256B-aligned regions)
    char* w = (char*)d_ws;
    size_t o = 0;
    auto alloc = [&](size_t bytes) { size_t cur = o; o += (bytes + 255) & ~255ULL; return cur; };
    int*   off   = (int*)  (w + alloc((size_t)(N + 1) * 4));
    int*   csr   = (int*)  (w + alloc((size_t)E * 4));
    unsigned int* pairs = (unsigned int*)(w + alloc((size_t)E * 4));
    unsigned int* HcT = (unsigned int*)(w + alloc((size_t)CB * NBUK * 4));
    unsigned int* Bb  = (unsigned int*)(w + alloc((size_t)CB * NBUK * 4));
    unsigned int* S   = (unsigned int*)(w + alloc((size_t)(NBUK + 1) * 4));
    unsigned short* xb = (unsigned short*)(w + alloc((size_t)NROWP * F_IN * 2));
    unsigned short* feat1b = (unsigned short*)(w + alloc((size_t)N * F1 * 2));
    float* el1   = (float*)(w + alloc((size_t)N * H1 * 4));
    float* er1   = (float*)(w + alloc((size_t)N * H1 * 4));
    float* h1    = (float*)(w + alloc((size_t)N * F1 * 4));
    unsigned short* feat2b = (unsigned short*)(w + alloc((size_t)N * F2 * 2));
    float* el2   = (float*)(w + alloc((size_t)N * H2 * 4));
    float* er2   = (float*)(w + alloc((size_t)N * H2 * 4));
    unsigned short* W1h = (unsigned short*)(w + alloc((size_t)F_IN * F1 * 2));
    unsigned short* W1l = (unsigned short*)(w + alloc((size_t)F_IN * F1 * 2));
    unsigned short* W2h = (unsigned short*)(w + alloc((size_t)F1 * F2 * 2));
    unsigned short* W2l = (unsigned short*)(w + alloc((size_t)F1 * F2 * 2));
    (void)ws_size; (void)n_in; (void)out_size;

    // ---- CSR build: bucketed counting sort (4 kernels, full grid width each) ----
    chist<<<CB, 256, 0, stream>>>(dst, HcT, E, NBUK);
    bscan<<<1, 512, 0, stream>>>(HcT, Bb, S, NBUK);
    cscat<<<CB, 256, 0, stream>>>(src, dst, Bb, S, pairs, E, NBUK);
    fscat<<<NBUK, 256, 0, stream>>>(pairs, S, off, csr, N, E);

    // ---- prep: weight split+swizzle and X swizzle, one launch ----
    prep_kernel<<<WBLK + (NROWP + 7) / 8, 256, 0, stream>>>(
        W1, W1h, W1l, W2, W2h, W2l, x, xb, N, NROWP);

    // ---- layer 1 ----
    gemm1_mfma<<<NBLK1, 256, 0, stream>>>(
        xb, W1h, W1l, al1, ar1, feat1b, el1, er1, N);
    agg1_kernel<<<(N + 3) / 4, 256, 0, stream>>>(off, csr, feat1b, el1, er1, b1, h1, N);

    // ---- layer 2 ----
    gemm2_mfma<<<(N + BM2 - 1) / BM2, 256, 0, stream>>>(
        h1, W2h, W2l, al2, ar2, feat2b, el2, er2, N);
    agg2_kernel<<<(N + 3) / 4, 256, 0, stream>>>(off, csr, feat2b, el2, er2, b2, (float*)d_out, N);
}

// Round 16
// 152.136 us; speedup vs baseline: 1.0604x; 1.0604x over previous
//
#include <hip/hip_runtime.h>

// ---------------- problem constants (match reference) ----------------
constexpr int F_IN = 256;
constexpr int H1 = 4, D1 = 32, F1 = H1 * D1;   // 128
constexpr int H2 = 1, D2 = 32, F2 = H2 * D2;   // 32
constexpr float NEG = 0.2f;

// CSR build params
constexpr int BW = 128;          // nodes per bucket (pow2)
constexpr int NBUK_MAX = 512;    // >= ceil(N/BW) = 391
constexpr int CB = 256;          // coarse blocks (one per CU)

typedef short short8 __attribute__((ext_vector_type(8)));
typedef float f32x4 __attribute__((ext_vector_type(4)));

__device__ inline float bf2f(unsigned short u) {
    unsigned int x = ((unsigned int)u) << 16;
    return __builtin_bit_cast(float, x);
}
__device__ inline unsigned short f2bf(float f) {
    __bf16 h = (__bf16)f;                      // RNE
    return __builtin_bit_cast(unsigned short, h);
}

// ---------------- CSR build: bucketed two-level counting sort (4 kernels) ----------------
__global__ __launch_bounds__(256) void chist(const int* __restrict__ dst,
                                             unsigned int* __restrict__ HcT,
                                             int E, int nbuk) {
    __shared__ unsigned int h[NBUK_MAX];
    int tid = threadIdx.x;
    for (int i = tid; i < nbuk; i += 256) h[i] = 0;
    __syncthreads();
    int epb = (E + CB - 1) / CB;
    int e0 = blockIdx.x * epb, e1 = min(e0 + epb, E);
    for (int e = e0 + tid; e < e1; e += 256)
        atomicAdd(&h[((unsigned)dst[e]) >> 7], 1u);
    __syncthreads();
    for (int i = tid; i < nbuk; i += 256) HcT[(size_t)i * CB + blockIdx.x] = h[i];
}

__global__ __launch_bounds__(512) void bscan(const unsigned int* __restrict__ HcT,
                                             unsigned int* __restrict__ Bb,
                                             unsigned int* __restrict__ S, int nbuk) {
    __shared__ unsigned int tot[NBUK_MAX];
    int t = threadIdx.x;
    unsigned int run = 0;
    if (t < nbuk) {
        const uint4* row = (const uint4*)(HcT + (size_t)t * CB);
#pragma unroll 8
        for (int b4 = 0; b4 < CB / 4; ++b4) {
            uint4 v = row[b4];
            int b = b4 * 4;
            Bb[(size_t)(b + 0) * nbuk + t] = run; run += v.x;
            Bb[(size_t)(b + 1) * nbuk + t] = run; run += v.y;
            Bb[(size_t)(b + 2) * nbuk + t] = run; run += v.z;
            Bb[(size_t)(b + 3) * nbuk + t] = run; run += v.w;
        }
    }
    tot[t] = (t < nbuk) ? run : 0;
    __syncthreads();
    for (int o = 1; o < NBUK_MAX; o <<= 1) {
        unsigned int v = (t >= o) ? tot[t - o] : 0;
        __syncthreads();
        tot[t] += v;
        __syncthreads();
    }
    if (t < nbuk) S[t] = tot[t] - run;          // exclusive
    if (t == nbuk - 1) S[nbuk] = tot[t];        // == E
}

__global__ __launch_bounds__(256) void cscat(const int* __restrict__ src,
                                             const int* __restrict__ dst,
                                             const unsigned int* __restrict__ Bb,
                                             const unsigned int* __restrict__ S,
                                             unsigned int* __restrict__ pairs, int E, int nbuk) {
    __shared__ unsigned int h[NBUK_MAX];
    int tid = threadIdx.x;
    for (int i = tid; i < nbuk; i += 256)
        h[i] = S[i] + Bb[(size_t)blockIdx.x * nbuk + i];
    __syncthreads();
    int epb = (E + CB - 1) / CB;
    int e0 = blockIdx.x * epb, e1 = min(e0 + epb, E);
    for (int e = e0 + tid; e < e1; e += 256) {
        int d = dst[e];
        int k = ((unsigned)d) >> 7;
        unsigned int p = atomicAdd(&h[k], 1u);
        pairs[p] = ((unsigned int)(d & 127) << 17) | (unsigned int)src[e];
    }
}

__global__ __launch_bounds__(256) void fscat(const unsigned int* __restrict__ pairs,
                                             const unsigned int* __restrict__ S,
                                             int* __restrict__ off, int* __restrict__ csr,
                                             int n, int E) {
    int k = blockIdx.x;
    int tid = threadIdx.x;
    unsigned int s0 = S[k], s1 = S[k + 1];
    __shared__ unsigned int cnt[BW];
    __shared__ unsigned int ex[BW];
    if (tid < BW) cnt[tid] = 0;
    __syncthreads();
    for (unsigned int i = s0 + tid; i < s1; i += 256)
        atomicAdd(&cnt[pairs[i] >> 17], 1u);
    __syncthreads();
    unsigned int orig = (tid < BW) ? cnt[tid] : 0;
    if (tid < BW) ex[tid] = orig;
    __syncthreads();
    for (int o = 1; o < BW; o <<= 1) {
        unsigned int v = (tid < BW && tid >= (unsigned)o) ? ex[tid - o] : 0;
        __syncthreads();
        if (tid < BW) ex[tid] += v;
        __syncthreads();
    }
    if (tid < BW) {
        ex[tid] -= orig;                        // exclusive within bucket
        int node = k * BW + tid;
        if (node < n) off[node] = (int)(s0 + ex[tid]);
    }
    if (tid < BW) cnt[tid] = 0;
    __syncthreads();
    for (unsigned int i = s0 + tid; i < s1; i += 256) {
        unsigned int pr = pairs[i];
        int loc = pr >> 17;
        unsigned int r = atomicAdd(&cnt[loc], 1u);
        csr[s0 + ex[loc] + r] = (int)(pr & 0x1FFFFu);
    }
    if (k == 0 && tid == 0) off[n] = E;
}

// ---------------- prep: W split+swizzle AND X swizzle in one launch ----------------
__device__ inline void wsplit_one(const float* W, unsigned short* Wh, unsigned short* Wl,
                                  int idx, int C) {
    int j    = idx & 7;
    int lane = (idx >> 3) & 63;
    int t    = idx >> 9;
    int FC   = C >> 4;
    int fc   = t % FC, ks = t / FC;
    int k = ks * 32 + (lane >> 4) * 8 + j;
    int c = fc * 16 + (lane & 15);
    float v = W[(size_t)k * C + c];
    __bf16 h = (__bf16)v;
    float hv = (float)h;
    __bf16 lo = (__bf16)(v - hv);
    Wh[idx] = __builtin_bit_cast(unsigned short, h);
    Wl[idx] = __builtin_bit_cast(unsigned short, lo);
}

constexpr int WBLK = (F_IN * F1 + F1 * F2) / 256;   // 144

__global__ __launch_bounds__(256) void prep_kernel(
    const float* __restrict__ W1, unsigned short* __restrict__ W1h,
    unsigned short* __restrict__ W1l,
    const float* __restrict__ W2, unsigned short* __restrict__ W2h,
    unsigned short* __restrict__ W2l,
    const float* __restrict__ x, unsigned short* __restrict__ xb,
    int n, int nrow_pad)
{
    int bid = blockIdx.x;
    if (bid < WBLK) {
        int idx = bid * 256 + threadIdx.x;
        constexpr int N1 = F_IN * F1;
        if (idx < N1) wsplit_one(W1, W1h, W1l, idx, F1);
        else wsplit_one(W2, W2h, W2l, idx - N1, F2);
        return;
    }
    // X swizzle: x[N][256] f32 -> bf16 A-fragments
    int tid = threadIdx.x;
    int lane = tid & 63;
    int wid = tid >> 6;
    int half = lane >> 5;
    int l32 = lane & 31;
    int ks = l32 >> 2;
    int khi = l32 & 3;
    int row = (bid - WBLK) * 8 + wid * 2 + half;
    if (row >= nrow_pad) return;
    float v[8];
    if (row < n) {
        const float* p = x + (size_t)row * F_IN + ks * 32 + khi * 8;
        float4 a = *(const float4*)p;
        float4 b = *(const float4*)(p + 4);
        v[0] = a.x; v[1] = a.y; v[2] = a.z; v[3] = a.w;
        v[4] = b.x; v[5] = b.y; v[6] = b.z; v[7] = b.w;
    } else {
#pragma unroll
        for (int j = 0; j < 8; ++j) v[j] = 0.f;
    }
    short8 s;
#pragma unroll
    for (int j = 0; j < 8; ++j) s[j] = (short)f2bf(v[j]);
    int frag16 = row >> 4;
    int fragLane = (row & 15) | (khi << 4);
    *(short8*)(xb + (((size_t)frag16 * 8 + ks) * 64 + fragLane) * 8) = s;
}

// ---------------- Layer-1 GEMM: no LDS, both operands pre-swizzled, fused el/er ----------
constexpr int BM1 = 64;
__global__ __launch_bounds__(256) void gemm1_mfma(
    const unsigned short* __restrict__ Xb,
    const unsigned short* __restrict__ Wh,
    const unsigned short* __restrict__ Wl,
    const float* __restrict__ alv, const float* __restrict__ arv,
    unsigned short* __restrict__ outb,
    float* __restrict__ el, float* __restrict__ er, int n)
{
    const int tid  = threadIdx.x;
    const int lane = tid & 63;
    const int wid  = tid >> 6;
    const int wrow = (wid >> 1) * 32;           // 0 or 32
    const int wcol = (wid & 1) * 64;            // 0 or 64
    const int wc16 = wcol >> 4;
    const int row0 = blockIdx.x * BM1;
    const int l16  = lane & 15;
    const int khi  = lane >> 4;                 // 0..3
    const int fbase = blockIdx.x * 4 + (wid >> 1) * 2;  // frag16 index for mi=0

    f32x4 acc[2][4];
#pragma unroll
    for (int mi = 0; mi < 2; ++mi)
#pragma unroll
        for (int ni = 0; ni < 4; ++ni) acc[mi][ni] = f32x4{0.f, 0.f, 0.f, 0.f};

#pragma unroll
    for (int ks = 0; ks < 8; ++ks) {
        short8 ah[2];
#pragma unroll
        for (int mi = 0; mi < 2; ++mi)
            ah[mi] = *(const short8*)(Xb + (((size_t)(fbase + mi) * 8 + ks) * 64 + lane) * 8);

        short8 bh[4], bl[4];
#pragma unroll
        for (int ni = 0; ni < 4; ++ni) {
            int base = ((ks * 8 + wc16 + ni) * 64 + lane) * 8;
            bh[ni] = *(const short8*)(Wh + base);
            bl[ni] = *(const short8*)(Wl + base);
        }

#pragma unroll
        for (int mi = 0; mi < 2; ++mi)
#pragma unroll
            for (int ni = 0; ni < 4; ++ni) {
                acc[mi][ni] = __builtin_amdgcn_mfma_f32_16x16x32_bf16(ah[mi], bl[ni], acc[mi][ni], 0, 0, 0);
                acc[mi][ni] = __builtin_amdgcn_mfma_f32_16x16x32_bf16(ah[mi], bh[ni], acc[mi][ni], 0, 0, 0);
            }
    }

    // ---- epilogue: bf16 feat store + fused el/er ----
    const int hh0 = wcol >> 5;                  // first head this wave covers (0 or 2)
    float alr[2][2], arr[2][2];
#pragma unroll
    for (int t = 0; t < 2; ++t) {
        int head = hh0 + t;
        alr[t][0] = alv[head * 32 + l16];
        alr[t][1] = alv[head * 32 + 16 + l16];
        arr[t][0] = arv[head * 32 + l16];
        arr[t][1] = arv[head * 32 + 16 + l16];
    }

#pragma unroll
    for (int mi = 0; mi < 2; ++mi) {
        int rbase = row0 + wrow + mi * 16 + khi * 4;
#pragma unroll
        for (int rr = 0; rr < 4; ++rr) {
            int row = rbase + rr;
            bool ok = row < n;
            if (ok) {
#pragma unroll
                for (int ni = 0; ni < 4; ++ni)
                    outb[(size_t)row * F1 + wcol + ni * 16 + l16] = f2bf(acc[mi][ni][rr]);
            }
#pragma unroll
            for (int t = 0; t < 2; ++t) {
                float pel = acc[mi][2 * t][rr] * alr[t][0] + acc[mi][2 * t + 1][rr] * alr[t][1];
                float per = acc[mi][2 * t][rr] * arr[t][0] + acc[mi][2 * t + 1][rr] * arr[t][1];
#pragma unroll
                for (int o = 1; o < 16; o <<= 1) {
                    pel += __shfl_xor(pel, o);
                    per += __shfl_xor(per, o);
                }
                if (ok && l16 == 0) {
                    el[(size_t)row * H1 + hh0 + t] = pel;
                    er[(size_t)row * H1 + hh0 + t] = per;
                }
            }
        }
    }
}

// ---------------- Layer-2 GEMM: LDS-staged X + swizzled W + fused el/er; bf16 out ----------
constexpr int BM2 = 64;
__global__ __launch_bounds__(256) void gemm2_mfma(
    const float* __restrict__ X,
    const unsigned short* __restrict__ Wh,
    const unsigned short* __restrict__ Wl,
    const float* __restrict__ alv, const float* __restrict__ arv,
    unsigned short* __restrict__ outb,
    float* __restrict__ el, float* __restrict__ er, int n)
{
    __shared__ float xs[32 * BM2 * 4];          // 32 KB
    const int tid  = threadIdx.x;
    const int lane = tid & 63;
    const int wid  = tid >> 6;
    const int wrow = wid * 16;
    const int row0 = blockIdx.x * BM2;
    const int l16  = lane & 15;
    const int khi  = lane >> 4;

    {
        int gr = row0 + lane;
        gr = gr < n ? gr : (n - 1);
        const float* rowp = X + (size_t)gr * F1;
#pragma unroll
        for (int i = 0; i < 8; ++i) {
            int kc = wid * 8 + i;
            const float* srcp = rowp + kc * 4;
            float* dstf = &xs[kc * BM2 * 4];
            __builtin_amdgcn_global_load_lds(
                (const __attribute__((address_space(1))) unsigned int*)srcp,
                (__attribute__((address_space(3))) unsigned int*)dstf,
                16, 0, 0);
        }
    }
    asm volatile("s_waitcnt vmcnt(0)" ::: "memory");
    __syncthreads();

    f32x4 acc[2];
#pragma unroll
    for (int ni = 0; ni < 2; ++ni) acc[ni] = f32x4{0.f, 0.f, 0.f, 0.f};

    const int rt = wrow + l16;

#pragma unroll
    for (int ks = 0; ks < 4; ++ks) {
        const int kc = ks * 8 + khi * 2;

        short8 bh[2], bl[2];
#pragma unroll
        for (int ni = 0; ni < 2; ++ni) {
            int base = ((ks * 2 + ni) * 64 + lane) * 8;
            bh[ni] = *(const short8*)(Wh + base);
            bl[ni] = *(const short8*)(Wl + base);
        }

        float4 xa0 = *(const float4*)&xs[(kc + 0) * BM2 * 4 + rt * 4];
        float4 xa1 = *(const float4*)&xs[(kc + 1) * BM2 * 4 + rt * 4];
        float v[8] = {xa0.x, xa0.y, xa0.z, xa0.w, xa1.x, xa1.y, xa1.z, xa1.w};
        short8 ah, al8;
#pragma unroll
        for (int j = 0; j < 8; ++j) {
            __bf16 h = (__bf16)v[j];
            float hv = (float)h;
            __bf16 lo = (__bf16)(v[j] - hv);
            ah[j] = __builtin_bit_cast(short, h);
            al8[j] = __builtin_bit_cast(short, lo);
        }

#pragma unroll
        for (int ni = 0; ni < 2; ++ni) {
            acc[ni] = __builtin_amdgcn_mfma_f32_16x16x32_bf16(al8, bh[ni], acc[ni], 0, 0, 0);
            acc[ni] = __builtin_amdgcn_mfma_f32_16x16x32_bf16(ah, bl[ni], acc[ni], 0, 0, 0);
            acc[ni] = __builtin_amdgcn_mfma_f32_16x16x32_bf16(ah, bh[ni], acc[ni], 0, 0, 0);
        }
    }

    float al0 = alv[l16], al1c = alv[16 + l16];
    float ar0 = arv[l16], ar1c = arv[16 + l16];

    int rbase = row0 + wrow + khi * 4;
#pragma unroll
    for (int rr = 0; rr < 4; ++rr) {
        int row = rbase + rr;
        bool ok = row < n;
        if (ok) {
#pragma unroll
            for (int ni = 0; ni < 2; ++ni)
                outb[(size_t)row * F2 + ni * 16 + l16] = f2bf(acc[ni][rr]);
        }
        float pel = acc[0][rr] * al0 + acc[1][rr] * al1c;
        float per = acc[0][rr] * ar0 + acc[1][rr] * ar1c;
#pragma unroll
        for (int o = 1; o < 16; o <<= 1) {
            pel += __shfl_xor(pel, o);
            per += __shfl_xor(per, o);
        }
        if (ok && l16 == 0) {
            el[row] = pel;
            er[row] = per;
        }
    }
}

// ---------------- Aggregation layer 1: bf16 gather, 8 edges in flight ----------------
__global__ __launch_bounds__(256) void agg1_kernel(
    const int* __restrict__ off, const int* __restrict__ csr_src,
    const unsigned short* __restrict__ featb, const float* __restrict__ el,
    const float* __restrict__ er, const float* __restrict__ b,
    float* __restrict__ out, int n)
{
    int wid = (blockIdx.x * 256 + threadIdx.x) >> 6;   // node
    int lane = threadIdx.x & 63;
    if (wid >= n) return;
    int c0 = (lane & 31) * 4;
    int h = (lane & 31) >> 3;
    int half = lane >> 5;
    float erv = er[(size_t)wid * H1 + h];
    float sw = 0.f;
    float4 acc = {0.f, 0.f, 0.f, 0.f};
    int jb = off[wid], je = off[wid + 1];
    int j = jb + half;
    for (; j + 6 < je; j += 8) {
        int s0 = csr_src[j];
        int s1 = csr_src[j + 2];
        int s2 = csr_src[j + 4];
        int s3 = csr_src[j + 6];
        ushort4 u0 = *(const ushort4*)(featb + (size_t)s0 * F1 + c0);
        ushort4 u1 = *(const ushort4*)(featb + (size_t)s1 * F1 + c0);
        ushort4 u2 = *(const ushort4*)(featb + (size_t)s2 * F1 + c0);
        ushort4 u3 = *(const ushort4*)(featb + (size_t)s3 * F1 + c0);
        float t0 = el[(size_t)s0 * H1 + h] + erv;
        float t1 = el[(size_t)s1 * H1 + h] + erv;
        float t2 = el[(size_t)s2 * H1 + h] + erv;
        float t3 = el[(size_t)s3 * H1 + h] + erv;
        t0 = t0 > 0.f ? t0 : NEG * t0;
        t1 = t1 > 0.f ? t1 : NEG * t1;
        t2 = t2 > 0.f ? t2 : NEG * t2;
        t3 = t3 > 0.f ? t3 : NEG * t3;
        float w0 = __expf(t0), w1 = __expf(t1), w2 = __expf(t2), w3 = __expf(t3);
        sw += (w0 + w1) + (w2 + w3);
        acc.x = fmaf(w0, bf2f(u0.x), fmaf(w1, bf2f(u1.x), fmaf(w2, bf2f(u2.x), fmaf(w3, bf2f(u3.x), acc.x))));
        acc.y = fmaf(w0, bf2f(u0.y), fmaf(w1, bf2f(u1.y), fmaf(w2, bf2f(u2.y), fmaf(w3, bf2f(u3.y), acc.y))));
        acc.z = fmaf(w0, bf2f(u0.z), fmaf(w1, bf2f(u1.z), fmaf(w2, bf2f(u2.z), fmaf(w3, bf2f(u3.z), acc.z))));
        acc.w = fmaf(w0, bf2f(u0.w), fmaf(w1, bf2f(u1.w), fmaf(w2, bf2f(u2.w), fmaf(w3, bf2f(u3.w), acc.w))));
    }
    for (; j < je; j += 2) {
        int s = csr_src[j];
        ushort4 u = *(const ushort4*)(featb + (size_t)s * F1 + c0);
        float t = el[(size_t)s * H1 + h] + erv;
        t = t > 0.f ? t : NEG * t;
        float w = __expf(t);
        sw += w;
        acc.x = fmaf(w, bf2f(u.x), acc.x);
        acc.y = fmaf(w, bf2f(u.y), acc.y);
        acc.z = fmaf(w, bf2f(u.z), acc.z);
        acc.w = fmaf(w, bf2f(u.w), acc.w);
    }
    acc.x += __shfl_xor(acc.x, 32);
    acc.y += __shfl_xor(acc.y, 32);
    acc.z += __shfl_xor(acc.z, 32);
    acc.w += __shfl_xor(acc.w, 32);
    sw    += __shfl_xor(sw, 32);
    if (half == 0) {
        float inv = 1.f / fmaxf(sw, 1e-16f);
        float4 bb = *(const float4*)(b + c0);
        float4 t = {acc.x * inv + bb.x, acc.y * inv + bb.y,
                    acc.z * inv + bb.z, acc.w * inv + bb.w};
        *(float4*)(out + (size_t)wid * F1 + c0) = t;
    }
}

// ---------------- Aggregation layer 2: bf16 gather, 16 edges in flight ----------------
__global__ __launch_bounds__(256) void agg2_kernel(
    const int* __restrict__ off, const int* __restrict__ csr_src,
    const unsigned short* __restrict__ featb, const float* __restrict__ el,
    const float* __restrict__ er, const float* __restrict__ b,
    float* __restrict__ out, int n)
{
    int wid = (blockIdx.x * 256 + threadIdx.x) >> 6;   // node
    int lane = threadIdx.x & 63;
    if (wid >= n) return;
    int c0 = (lane & 7) * 4;
    int grp = lane >> 3;
    float erv = er[wid];
    float sw = 0.f;
    float4 acc = {0.f, 0.f, 0.f, 0.f};
    int jb = off[wid], je = off[wid + 1];
    int j = jb + grp;
    for (; j + 8 < je; j += 16) {
        int s0 = csr_src[j];
        int s1 = csr_src[j + 8];
        ushort4 u0 = *(const ushort4*)(featb + (size_t)s0 * F2 + c0);
        ushort4 u1 = *(const ushort4*)(featb + (size_t)s1 * F2 + c0);
        float t0 = el[s0] + erv;
        float t1 = el[s1] + erv;
        t0 = t0 > 0.f ? t0 : NEG * t0;
        t1 = t1 > 0.f ? t1 : NEG * t1;
        float w0 = __expf(t0);
        float w1 = __expf(t1);
        sw += w0 + w1;
        acc.x = fmaf(w0, bf2f(u0.x), fmaf(w1, bf2f(u1.x), acc.x));
        acc.y = fmaf(w0, bf2f(u0.y), fmaf(w1, bf2f(u1.y), acc.y));
        acc.z = fmaf(w0, bf2f(u0.z), fmaf(w1, bf2f(u1.z), acc.z));
        acc.w = fmaf(w0, bf2f(u0.w), fmaf(w1, bf2f(u1.w), acc.w));
    }
    for (; j < je; j += 8) {
        int s = csr_src[j];
        ushort4 u = *(const ushort4*)(featb + (size_t)s * F2 + c0);
        float t = el[s] + erv;
        t = t > 0.f ? t : NEG * t;
        float w = __expf(t);
        sw += w;
        acc.x = fmaf(w, bf2f(u.x), acc.x);
        acc.y = fmaf(w, bf2f(u.y), acc.y);
        acc.z = fmaf(w, bf2f(u.z), acc.z);
        acc.w = fmaf(w, bf2f(u.w), acc.w);
    }
#pragma unroll
    for (int o = 8; o < 64; o <<= 1) {
        acc.x += __shfl_xor(acc.x, o);
        acc.y += __shfl_xor(acc.y, o);
        acc.z += __shfl_xor(acc.z, o);
        acc.w += __shfl_xor(acc.w, o);
        sw    += __shfl_xor(sw, o);
    }
    if (lane < 8) {
        float inv = 1.f / fmaxf(sw, 1e-16f);
        float4 bb = *(const float4*)(b + c0);
        float4 t = {acc.x * inv + bb.x, acc.y * inv + bb.y,
                    acc.z * inv + bb.z, acc.w * inv + bb.w};
        *(float4*)(out + (size_t)wid * F2 + c0) = t;
    }
}

// ---------------- launch ----------------
extern "C" void kernel_launch(void* const* d_in, const int* in_sizes, int n_in,
                              void* d_out, int out_size, void* d_ws, size_t ws_size,
                              hipStream_t stream) {
    const float* x   = (const float*)d_in[0];
    const float* W1  = (const float*)d_in[1];
    const float* al1 = (const float*)d_in[2];
    const float* ar1 = (const float*)d_in[3];
    const float* b1  = (const float*)d_in[4];
    const float* W2  = (const float*)d_in[5];
    const float* al2 = (const float*)d_in[6];
    const float* ar2 = (const float*)d_in[7];
    const float* b2  = (const float*)d_in[8];
    const int*   src = (const int*)d_in[9];
    const int*   dst = (const int*)d_in[10];

    const int N = in_sizes[0] / F_IN;
    const int E = in_sizes[9];
    const int NBUK = (N + BW - 1) / BW;          // 391
    const int NBLK1 = (N + BM1 - 1) / BM1;       // 782
    const int NROWP = NBLK1 * BM1;               // padded rows (50048)

    // workspace layout (256B-aligned regions)
    char* w = (char*)d_ws;
    size_t o = 0;
    auto alloc = [&](size_t bytes) { size_t cur = o; o += (bytes + 255) & ~255ULL; return cur; };
    int*   off   = (int*)  (w + alloc((size_t)(N + 1) * 4));
    int*   csr   = (int*)  (w + alloc((size_t)E * 4));
    unsigned int* pairs = (unsigned int*)(w + alloc((size_t)E * 4));
    unsigned int* HcT = (unsigned int*)(w + alloc((size_t)CB * NBUK * 4));
    unsigned int* Bb  = (unsigned int*)(w + alloc((size_t)CB * NBUK * 4));
    unsigned int* S   = (unsigned int*)(w + alloc((size_t)(NBUK + 1) * 4));
    unsigned short* xb = (unsigned short*)(w + alloc((size_t)NROWP * F_IN * 2));
    unsigned short* feat1b = (unsigned short*)(w + alloc((size_t)N * F1 * 2));
    float* el1   = (float*)(w + alloc((size_t)N * H1 * 4));
    float* er1   = (float*)(w + alloc((size_t)N * H1 * 4));
    float* h1    = (float*)(w + alloc((size_t)N * F1 * 4));
    unsigned short* feat2b = (unsigned short*)(w + alloc((size_t)N * F2 * 2));
    float* el2   = (float*)(w + alloc((size_t)N * H2 * 4));
    float* er2   = (float*)(w + alloc((size_t)N * H2 * 4));
    unsigned short* W1h = (unsigned short*)(w + alloc((size_t)F_IN * F1 * 2));
    unsigned short* W1l = (unsigned short*)(w + alloc((size_t)F_IN * F1 * 2));
    unsigned short* W2h = (unsigned short*)(w + alloc((size_t)F1 * F2 * 2));
    unsigned short* W2l = (unsigned short*)(w + alloc((size_t)F1 * F2 * 2));
    (void)ws_size; (void)n_in; (void)out_size;

    // ---- CSR build: bucketed counting sort (4 kernels, full grid width each) ----
    chist<<<CB, 256, 0, stream>>>(dst, HcT, E, NBUK);
    bscan<<<1, 512, 0, stream>>>(HcT, Bb, S, NBUK);
    cscat<<<CB, 256, 0, stream>>>(src, dst, Bb, S, pairs, E, NBUK);
    fscat<<<NBUK, 256, 0, stream>>>(pairs, S, off, csr, N, E);

    // ---- prep: weight split+swizzle and X swizzle, one launch ----
    prep_kernel<<<WBLK + (NROWP + 7) / 8, 256, 0, stream>>>(
        W1, W1h, W1l, W2, W2h, W2l, x, xb, N, NROWP);

    // ---- layer 1 ----
    gemm1_mfma<<<NBLK1, 256, 0, stream>>>(
        xb, W1h, W1l, al1, ar1, feat1b, el1, er1, N);
    agg1_kernel<<<(N + 3) / 4, 256, 0, stream>>>(off, csr, feat1b, el1, er1, b1, h1, N);

    // ---- layer 2 ----
    gemm2_mfma<<<(N + BM2 - 1) / BM2, 256, 0, stream>>>(
        h1, W2h, W2l, al2, ar2, feat2b, el2, er2, N);
    agg2_kernel<<<(N + 3) / 4, 256, 0, stream>>>(off, csr, feat2b, el2, er2, b2, (float*)d_out, N);
}

// Round 17
// 146.905 us; speedup vs baseline: 1.0982x; 1.0356x over previous
//
#include <hip/hip_runtime.h>

// ---------------- problem constants (match reference) ----------------
constexpr int F_IN = 256;
constexpr int H1 = 4, D1 = 32, F1 = H1 * D1;   // 128
constexpr int H2 = 1, D2 = 32, F2 = H2 * D2;   // 32
constexpr float NEG = 0.2f;

// CSR build params
constexpr int BW = 128;          // nodes per bucket (pow2)
constexpr int NBUK_MAX = 512;    // >= ceil(N/BW) = 391
constexpr int CB = 256;          // coarse blocks (one per CU)

typedef short short8 __attribute__((ext_vector_type(8)));
typedef float f32x4 __attribute__((ext_vector_type(4)));

__device__ inline float bf2f(unsigned short u) {
    unsigned int x = ((unsigned int)u) << 16;
    return __builtin_bit_cast(float, x);
}
__device__ inline unsigned short f2bf(float f) {
    __bf16 h = (__bf16)f;                      // RNE
    return __builtin_bit_cast(unsigned short, h);
}

// ---------------- CSR build: bucketed two-level counting sort (4 kernels) ----------------
__global__ __launch_bounds__(256) void chist(const int* __restrict__ dst,
                                             unsigned int* __restrict__ HcT,
                                             int E, int nbuk) {
    __shared__ unsigned int h[NBUK_MAX];
    int tid = threadIdx.x;
    for (int i = tid; i < nbuk; i += 256) h[i] = 0;
    __syncthreads();
    int epb = (E + CB - 1) / CB;
    int e0 = blockIdx.x * epb, e1 = min(e0 + epb, E);
    for (int e = e0 + tid; e < e1; e += 256)
        atomicAdd(&h[((unsigned)dst[e]) >> 7], 1u);
    __syncthreads();
    for (int i = tid; i < nbuk; i += 256) HcT[(size_t)i * CB + blockIdx.x] = h[i];
}

__global__ __launch_bounds__(512) void bscan(const unsigned int* __restrict__ HcT,
                                             unsigned int* __restrict__ Bb,
                                             unsigned int* __restrict__ S, int nbuk) {
    __shared__ unsigned int tot[NBUK_MAX];
    int t = threadIdx.x;
    unsigned int run = 0;
    if (t < nbuk) {
        const uint4* row = (const uint4*)(HcT + (size_t)t * CB);
#pragma unroll 8
        for (int b4 = 0; b4 < CB / 4; ++b4) {
            uint4 v = row[b4];
            int b = b4 * 4;
            Bb[(size_t)(b + 0) * nbuk + t] = run; run += v.x;
            Bb[(size_t)(b + 1) * nbuk + t] = run; run += v.y;
            Bb[(size_t)(b + 2) * nbuk + t] = run; run += v.z;
            Bb[(size_t)(b + 3) * nbuk + t] = run; run += v.w;
        }
    }
    tot[t] = (t < nbuk) ? run : 0;
    __syncthreads();
    for (int o = 1; o < NBUK_MAX; o <<= 1) {
        unsigned int v = (t >= o) ? tot[t - o] : 0;
        __syncthreads();
        tot[t] += v;
        __syncthreads();
    }
    if (t < nbuk) S[t] = tot[t] - run;          // exclusive
    if (t == nbuk - 1) S[nbuk] = tot[t];        // == E
}

__global__ __launch_bounds__(256) void cscat(const int* __restrict__ src,
                                             const int* __restrict__ dst,
                                             const unsigned int* __restrict__ Bb,
                                             const unsigned int* __restrict__ S,
                                             unsigned int* __restrict__ pairs, int E, int nbuk) {
    __shared__ unsigned int h[NBUK_MAX];
    int tid = threadIdx.x;
    for (int i = tid; i < nbuk; i += 256)
        h[i] = S[i] + Bb[(size_t)blockIdx.x * nbuk + i];
    __syncthreads();
    int epb = (E + CB - 1) / CB;
    int e0 = blockIdx.x * epb, e1 = min(e0 + epb, E);
    for (int e = e0 + tid; e < e1; e += 256) {
        int d = dst[e];
        int k = ((unsigned)d) >> 7;
        unsigned int p = atomicAdd(&h[k], 1u);
        pairs[p] = ((unsigned int)(d & 127) << 17) | (unsigned int)src[e];
    }
}

__global__ __launch_bounds__(256) void fscat(const unsigned int* __restrict__ pairs,
                                             const unsigned int* __restrict__ S,
                                             int* __restrict__ off, int* __restrict__ csr,
                                             int n, int E) {
    int k = blockIdx.x;
    int tid = threadIdx.x;
    unsigned int s0 = S[k], s1 = S[k + 1];
    __shared__ unsigned int cnt[BW];
    __shared__ unsigned int ex[BW];
    if (tid < BW) cnt[tid] = 0;
    __syncthreads();
    for (unsigned int i = s0 + tid; i < s1; i += 256)
        atomicAdd(&cnt[pairs[i] >> 17], 1u);
    __syncthreads();
    unsigned int orig = (tid < BW) ? cnt[tid] : 0;
    if (tid < BW) ex[tid] = orig;
    __syncthreads();
    for (int o = 1; o < BW; o <<= 1) {
        unsigned int v = (tid < BW && tid >= (unsigned)o) ? ex[tid - o] : 0;
        __syncthreads();
        if (tid < BW) ex[tid] += v;
        __syncthreads();
    }
    if (tid < BW) {
        ex[tid] -= orig;                        // exclusive within bucket
        int node = k * BW + tid;
        if (node < n) off[node] = (int)(s0 + ex[tid]);
    }
    if (tid < BW) cnt[tid] = 0;
    __syncthreads();
    for (unsigned int i = s0 + tid; i < s1; i += 256) {
        unsigned int pr = pairs[i];
        int loc = pr >> 17;
        unsigned int r = atomicAdd(&cnt[loc], 1u);
        csr[s0 + ex[loc] + r] = (int)(pr & 0x1FFFFu);
    }
    if (k == 0 && tid == 0) off[n] = E;
}

// ---------------- prep: W split+swizzle AND X swizzle in one launch ----------------
__device__ inline void wsplit_one(const float* W, unsigned short* Wh, unsigned short* Wl,
                                  int idx, int C) {
    int j    = idx & 7;
    int lane = (idx >> 3) & 63;
    int t    = idx >> 9;
    int FC   = C >> 4;
    int fc   = t % FC, ks = t / FC;
    int k = ks * 32 + (lane >> 4) * 8 + j;
    int c = fc * 16 + (lane & 15);
    float v = W[(size_t)k * C + c];
    __bf16 h = (__bf16)v;
    float hv = (float)h;
    __bf16 lo = (__bf16)(v - hv);
    Wh[idx] = __builtin_bit_cast(unsigned short, h);
    Wl[idx] = __builtin_bit_cast(unsigned short, lo);
}

constexpr int WBLK = (F_IN * F1 + F1 * F2) / 256;   // 144

__global__ __launch_bounds__(256) void prep_kernel(
    const float* __restrict__ W1, unsigned short* __restrict__ W1h,
    unsigned short* __restrict__ W1l,
    const float* __restrict__ W2, unsigned short* __restrict__ W2h,
    unsigned short* __restrict__ W2l,
    const float* __restrict__ x, unsigned short* __restrict__ xb,
    int n, int nrow_pad)
{
    int bid = blockIdx.x;
    if (bid < WBLK) {
        int idx = bid * 256 + threadIdx.x;
        constexpr int N1 = F_IN * F1;
        if (idx < N1) wsplit_one(W1, W1h, W1l, idx, F1);
        else wsplit_one(W2, W2h, W2l, idx - N1, F2);
        return;
    }
    // X swizzle: x[N][256] f32 -> bf16 A-fragments
    int tid = threadIdx.x;
    int lane = tid & 63;
    int wid = tid >> 6;
    int half = lane >> 5;
    int l32 = lane & 31;
    int ks = l32 >> 2;
    int khi = l32 & 3;
    int row = (bid - WBLK) * 8 + wid * 2 + half;
    if (row >= nrow_pad) return;
    float v[8];
    if (row < n) {
        const float* p = x + (size_t)row * F_IN + ks * 32 + khi * 8;
        float4 a = *(const float4*)p;
        float4 b = *(const float4*)(p + 4);
        v[0] = a.x; v[1] = a.y; v[2] = a.z; v[3] = a.w;
        v[4] = b.x; v[5] = b.y; v[6] = b.z; v[7] = b.w;
    } else {
#pragma unroll
        for (int j = 0; j < 8; ++j) v[j] = 0.f;
    }
    short8 s;
#pragma unroll
    for (int j = 0; j < 8; ++j) s[j] = (short)f2bf(v[j]);
    int frag16 = row >> 4;
    int fragLane = (row & 15) | (khi << 4);
    *(short8*)(xb + (((size_t)frag16 * 8 + ks) * 64 + fragLane) * 8) = s;
}

// ---------------- Layer-1 GEMM: no LDS, both operands pre-swizzled, fused el/er ----------
constexpr int BM1 = 64;
__global__ __launch_bounds__(256) void gemm1_mfma(
    const unsigned short* __restrict__ Xb,
    const unsigned short* __restrict__ Wh,
    const unsigned short* __restrict__ Wl,
    const float* __restrict__ alv, const float* __restrict__ arv,
    unsigned short* __restrict__ outb,
    float* __restrict__ el, float* __restrict__ er, int n)
{
    const int tid  = threadIdx.x;
    const int lane = tid & 63;
    const int wid  = tid >> 6;
    const int wrow = (wid >> 1) * 32;           // 0 or 32
    const int wcol = (wid & 1) * 64;            // 0 or 64
    const int wc16 = wcol >> 4;
    const int row0 = blockIdx.x * BM1;
    const int l16  = lane & 15;
    const int khi  = lane >> 4;                 // 0..3
    const int fbase = blockIdx.x * 4 + (wid >> 1) * 2;  // frag16 index for mi=0

    f32x4 acc[2][4];
#pragma unroll
    for (int mi = 0; mi < 2; ++mi)
#pragma unroll
        for (int ni = 0; ni < 4; ++ni) acc[mi][ni] = f32x4{0.f, 0.f, 0.f, 0.f};

#pragma unroll
    for (int ks = 0; ks < 8; ++ks) {
        short8 ah[2];
#pragma unroll
        for (int mi = 0; mi < 2; ++mi)
            ah[mi] = *(const short8*)(Xb + (((size_t)(fbase + mi) * 8 + ks) * 64 + lane) * 8);

        short8 bh[4], bl[4];
#pragma unroll
        for (int ni = 0; ni < 4; ++ni) {
            int base = ((ks * 8 + wc16 + ni) * 64 + lane) * 8;
            bh[ni] = *(const short8*)(Wh + base);
            bl[ni] = *(const short8*)(Wl + base);
        }

#pragma unroll
        for (int mi = 0; mi < 2; ++mi)
#pragma unroll
            for (int ni = 0; ni < 4; ++ni) {
                acc[mi][ni] = __builtin_amdgcn_mfma_f32_16x16x32_bf16(ah[mi], bl[ni], acc[mi][ni], 0, 0, 0);
                acc[mi][ni] = __builtin_amdgcn_mfma_f32_16x16x32_bf16(ah[mi], bh[ni], acc[mi][ni], 0, 0, 0);
            }
    }

    // ---- epilogue: bf16 feat store + fused el/er ----
    const int hh0 = wcol >> 5;                  // first head this wave covers (0 or 2)
    float alr[2][2], arr[2][2];
#pragma unroll
    for (int t = 0; t < 2; ++t) {
        int head = hh0 + t;
        alr[t][0] = alv[head * 32 + l16];
        alr[t][1] = alv[head * 32 + 16 + l16];
        arr[t][0] = arv[head * 32 + l16];
        arr[t][1] = arv[head * 32 + 16 + l16];
    }

#pragma unroll
    for (int mi = 0; mi < 2; ++mi) {
        int rbase = row0 + wrow + mi * 16 + khi * 4;
#pragma unroll
        for (int rr = 0; rr < 4; ++rr) {
            int row = rbase + rr;
            bool ok = row < n;
            if (ok) {
#pragma unroll
                for (int ni = 0; ni < 4; ++ni)
                    outb[(size_t)row * F1 + wcol + ni * 16 + l16] = f2bf(acc[mi][ni][rr]);
            }
#pragma unroll
            for (int t = 0; t < 2; ++t) {
                float pel = acc[mi][2 * t][rr] * alr[t][0] + acc[mi][2 * t + 1][rr] * alr[t][1];
                float per = acc[mi][2 * t][rr] * arr[t][0] + acc[mi][2 * t + 1][rr] * arr[t][1];
#pragma unroll
                for (int o = 1; o < 16; o <<= 1) {
                    pel += __shfl_xor(pel, o);
                    per += __shfl_xor(per, o);
                }
                if (ok && l16 == 0) {
                    el[(size_t)row * H1 + hh0 + t] = pel;
                    er[(size_t)row * H1 + hh0 + t] = per;
                }
            }
        }
    }
}

// ---------------- Layer-2 GEMM: bf16 h1 input (LDS-staged), pure-bf16 A, split-W ----------
constexpr int BM2 = 64;
__global__ __launch_bounds__(256) void gemm2_mfma(
    const unsigned short* __restrict__ Xb,   // h1 in bf16, [n][F1]
    const unsigned short* __restrict__ Wh,
    const unsigned short* __restrict__ Wl,
    const float* __restrict__ alv, const float* __restrict__ arv,
    unsigned short* __restrict__ outb,
    float* __restrict__ el, float* __restrict__ er, int n)
{
    __shared__ unsigned short xs[16 * BM2 * 8];   // 16 KB: [kc 0..15][row 0..63][8 bf16]
    const int tid  = threadIdx.x;
    const int lane = tid & 63;
    const int wid  = tid >> 6;
    const int wrow = wid * 16;
    const int row0 = blockIdx.x * BM2;
    const int l16  = lane & 15;
    const int khi  = lane >> 4;

    {
        int gr = row0 + lane;
        gr = gr < n ? gr : (n - 1);
        const unsigned short* rowp = Xb + (size_t)gr * F1;
#pragma unroll
        for (int i = 0; i < 4; ++i) {
            int kc = wid * 4 + i;                  // 16B chunk (8 bf16) of the row
            const unsigned short* srcp = rowp + kc * 8;
            unsigned short* dstp = &xs[kc * BM2 * 8];
            __builtin_amdgcn_global_load_lds(
                (const __attribute__((address_space(1))) unsigned int*)srcp,
                (__attribute__((address_space(3))) unsigned int*)dstp,
                16, 0, 0);
        }
    }
    asm volatile("s_waitcnt vmcnt(0)" ::: "memory");
    __syncthreads();

    f32x4 acc[2];
#pragma unroll
    for (int ni = 0; ni < 2; ++ni) acc[ni] = f32x4{0.f, 0.f, 0.f, 0.f};

    const int rt = wrow + l16;

#pragma unroll
    for (int ks = 0; ks < 4; ++ks) {
        const int kc = ks * 4 + khi;

        short8 bh[2], bl[2];
#pragma unroll
        for (int ni = 0; ni < 2; ++ni) {
            int base = ((ks * 2 + ni) * 64 + lane) * 8;
            bh[ni] = *(const short8*)(Wh + base);
            bl[ni] = *(const short8*)(Wl + base);
        }

        short8 ah = *(const short8*)&xs[(kc * BM2 + rt) * 8];

#pragma unroll
        for (int ni = 0; ni < 2; ++ni) {
            acc[ni] = __builtin_amdgcn_mfma_f32_16x16x32_bf16(ah, bl[ni], acc[ni], 0, 0, 0);
            acc[ni] = __builtin_amdgcn_mfma_f32_16x16x32_bf16(ah, bh[ni], acc[ni], 0, 0, 0);
        }
    }

    float al0 = alv[l16], al1c = alv[16 + l16];
    float ar0 = arv[l16], ar1c = arv[16 + l16];

    int rbase = row0 + wrow + khi * 4;
#pragma unroll
    for (int rr = 0; rr < 4; ++rr) {
        int row = rbase + rr;
        bool ok = row < n;
        if (ok) {
#pragma unroll
            for (int ni = 0; ni < 2; ++ni)
                outb[(size_t)row * F2 + ni * 16 + l16] = f2bf(acc[ni][rr]);
        }
        float pel = acc[0][rr] * al0 + acc[1][rr] * al1c;
        float per = acc[0][rr] * ar0 + acc[1][rr] * ar1c;
#pragma unroll
        for (int o = 1; o < 16; o <<= 1) {
            pel += __shfl_xor(pel, o);
            per += __shfl_xor(per, o);
        }
        if (ok && l16 == 0) {
            el[row] = pel;
            er[row] = per;
        }
    }
}

// ---------------- Aggregation layer 1: bf16 gather, 8 edges in flight; bf16 out ----------
__global__ __launch_bounds__(256) void agg1_kernel(
    const int* __restrict__ off, const int* __restrict__ csr_src,
    const unsigned short* __restrict__ featb, const float* __restrict__ el,
    const float* __restrict__ er, const float* __restrict__ b,
    unsigned short* __restrict__ outb, int n)
{
    int wid = (blockIdx.x * 256 + threadIdx.x) >> 6;   // node
    int lane = threadIdx.x & 63;
    if (wid >= n) return;
    int c0 = (lane & 31) * 4;
    int h = (lane & 31) >> 3;
    int half = lane >> 5;
    float erv = er[(size_t)wid * H1 + h];
    float sw = 0.f;
    float4 acc = {0.f, 0.f, 0.f, 0.f};
    int jb = off[wid], je = off[wid + 1];
    int j = jb + half;
    for (; j + 6 < je; j += 8) {
        int s0 = csr_src[j];
        int s1 = csr_src[j + 2];
        int s2 = csr_src[j + 4];
        int s3 = csr_src[j + 6];
        ushort4 u0 = *(const ushort4*)(featb + (size_t)s0 * F1 + c0);
        ushort4 u1 = *(const ushort4*)(featb + (size_t)s1 * F1 + c0);
        ushort4 u2 = *(const ushort4*)(featb + (size_t)s2 * F1 + c0);
        ushort4 u3 = *(const ushort4*)(featb + (size_t)s3 * F1 + c0);
        float t0 = el[(size_t)s0 * H1 + h] + erv;
        float t1 = el[(size_t)s1 * H1 + h] + erv;
        float t2 = el[(size_t)s2 * H1 + h] + erv;
        float t3 = el[(size_t)s3 * H1 + h] + erv;
        t0 = t0 > 0.f ? t0 : NEG * t0;
        t1 = t1 > 0.f ? t1 : NEG * t1;
        t2 = t2 > 0.f ? t2 : NEG * t2;
        t3 = t3 > 0.f ? t3 : NEG * t3;
        float w0 = __expf(t0), w1 = __expf(t1), w2 = __expf(t2), w3 = __expf(t3);
        sw += (w0 + w1) + (w2 + w3);
        acc.x = fmaf(w0, bf2f(u0.x), fmaf(w1, bf2f(u1.x), fmaf(w2, bf2f(u2.x), fmaf(w3, bf2f(u3.x), acc.x))));
        acc.y = fmaf(w0, bf2f(u0.y), fmaf(w1, bf2f(u1.y), fmaf(w2, bf2f(u2.y), fmaf(w3, bf2f(u3.y), acc.y))));
        acc.z = fmaf(w0, bf2f(u0.z), fmaf(w1, bf2f(u1.z), fmaf(w2, bf2f(u2.z), fmaf(w3, bf2f(u3.z), acc.z))));
        acc.w = fmaf(w0, bf2f(u0.w), fmaf(w1, bf2f(u1.w), fmaf(w2, bf2f(u2.w), fmaf(w3, bf2f(u3.w), acc.w))));
    }
    for (; j < je; j += 2) {
        int s = csr_src[j];
        ushort4 u = *(const ushort4*)(featb + (size_t)s * F1 + c0);
        float t = el[(size_t)s * H1 + h] + erv;
        t = t > 0.f ? t : NEG * t;
        float w = __expf(t);
        sw += w;
        acc.x = fmaf(w, bf2f(u.x), acc.x);
        acc.y = fmaf(w, bf2f(u.y), acc.y);
        acc.z = fmaf(w, bf2f(u.z), acc.z);
        acc.w = fmaf(w, bf2f(u.w), acc.w);
    }
    acc.x += __shfl_xor(acc.x, 32);
    acc.y += __shfl_xor(acc.y, 32);
    acc.z += __shfl_xor(acc.z, 32);
    acc.w += __shfl_xor(acc.w, 32);
    sw    += __shfl_xor(sw, 32);
    if (half == 0) {
        float inv = 1.f / fmaxf(sw, 1e-16f);
        float4 bb = *(const float4*)(b + c0);
        ushort4 t;
        t.x = f2bf(acc.x * inv + bb.x);
        t.y = f2bf(acc.y * inv + bb.y);
        t.z = f2bf(acc.z * inv + bb.z);
        t.w = f2bf(acc.w * inv + bb.w);
        *(ushort4*)(outb + (size_t)wid * F1 + c0) = t;
    }
}

// ---------------- Aggregation layer 2: bf16 gather, 16 edges in flight ----------------
__global__ __launch_bounds__(256) void agg2_kernel(
    const int* __restrict__ off, const int* __restrict__ csr_src,
    const unsigned short* __restrict__ featb, const float* __restrict__ el,
    const float* __restrict__ er, const float* __restrict__ b,
    float* __restrict__ out, int n)
{
    int wid = (blockIdx.x * 256 + threadIdx.x) >> 6;   // node
    int lane = threadIdx.x & 63;
    if (wid >= n) return;
    int c0 = (lane & 7) * 4;
    int grp = lane >> 3;
    float erv = er[wid];
    float sw = 0.f;
    float4 acc = {0.f, 0.f, 0.f, 0.f};
    int jb = off[wid], je = off[wid + 1];
    int j = jb + grp;
    for (; j + 8 < je; j += 16) {
        int s0 = csr_src[j];
        int s1 = csr_src[j + 8];
        ushort4 u0 = *(const ushort4*)(featb + (size_t)s0 * F2 + c0);
        ushort4 u1 = *(const ushort4*)(featb + (size_t)s1 * F2 + c0);
        float t0 = el[s0] + erv;
        float t1 = el[s1] + erv;
        t0 = t0 > 0.f ? t0 : NEG * t0;
        t1 = t1 > 0.f ? t1 : NEG * t1;
        float w0 = __expf(t0);
        float w1 = __expf(t1);
        sw += w0 + w1;
        acc.x = fmaf(w0, bf2f(u0.x), fmaf(w1, bf2f(u1.x), acc.x));
        acc.y = fmaf(w0, bf2f(u0.y), fmaf(w1, bf2f(u1.y), acc.y));
        acc.z = fmaf(w0, bf2f(u0.z), fmaf(w1, bf2f(u1.z), acc.z));
        acc.w = fmaf(w0, bf2f(u0.w), fmaf(w1, bf2f(u1.w), acc.w));
    }
    for (; j < je; j += 8) {
        int s = csr_src[j];
        ushort4 u = *(const ushort4*)(featb + (size_t)s * F2 + c0);
        float t = el[s] + erv;
        t = t > 0.f ? t : NEG * t;
        float w = __expf(t);
        sw += w;
        acc.x = fmaf(w, bf2f(u.x), acc.x);
        acc.y = fmaf(w, bf2f(u.y), acc.y);
        acc.z = fmaf(w, bf2f(u.z), acc.z);
        acc.w = fmaf(w, bf2f(u.w), acc.w);
    }
#pragma unroll
    for (int o = 8; o < 64; o <<= 1) {
        acc.x += __shfl_xor(acc.x, o);
        acc.y += __shfl_xor(acc.y, o);
        acc.z += __shfl_xor(acc.z, o);
        acc.w += __shfl_xor(acc.w, o);
        sw    += __shfl_xor(sw, o);
    }
    if (lane < 8) {
        float inv = 1.f / fmaxf(sw, 1e-16f);
        float4 bb = *(const float4*)(b + c0);
        float4 t = {acc.x * inv + bb.x, acc.y * inv + bb.y,
                    acc.z * inv + bb.z, acc.w * inv + bb.w};
        *(float4*)(out + (size_t)wid * F2 + c0) = t;
    }
}

// ---------------- launch ----------------
extern "C" void kernel_launch(void* const* d_in, const int* in_sizes, int n_in,
                              void* d_out, int out_size, void* d_ws, size_t ws_size,
                              hipStream_t stream) {
    const float* x   = (const float*)d_in[0];
    const float* W1  = (const float*)d_in[1];
    const float* al1 = (const float*)d_in[2];
    const float* ar1 = (const float*)d_in[3];
    const float* b1  = (const float*)d_in[4];
    const float* W2  = (const float*)d_in[5];
    const float* al2 = (const float*)d_in[6];
    const float* ar2 = (const float*)d_in[7];
    const float* b2  = (const float*)d_in[8];
    const int*   src = (const int*)d_in[9];
    const int*   dst = (const int*)d_in[10];

    const int N = in_sizes[0] / F_IN;
    const int E = in_sizes[9];
    const int NBUK = (N + BW - 1) / BW;          // 391
    const int NBLK1 = (N + BM1 - 1) / BM1;       // 782
    const int NROWP = NBLK1 * BM1;               // padded rows (50048)

    // workspace layout (256B-aligned regions)
    char* w = (char*)d_ws;
    size_t o = 0;
    auto alloc = [&](size_t bytes) { size_t cur = o; o += (bytes + 255) & ~255ULL; return cur; };
    int*   off   = (int*)  (w + alloc((size_t)(N + 1) * 4));
    int*   csr   = (int*)  (w + alloc((size_t)E * 4));
    unsigned int* pairs = (unsigned int*)(w + alloc((size_t)E * 4));
    unsigned int* HcT = (unsigned int*)(w + alloc((size_t)CB * NBUK * 4));
    unsigned int* Bb  = (unsigned int*)(w + alloc((size_t)CB * NBUK * 4));
    unsigned int* S   = (unsigned int*)(w + alloc((size_t)(NBUK + 1) * 4));
    unsigned short* xb = (unsigned short*)(w + alloc((size_t)NROWP * F_IN * 2));
    unsigned short* feat1b = (unsigned short*)(w + alloc((size_t)N * F1 * 2));
    float* el1   = (float*)(w + alloc((size_t)N * H1 * 4));
    float* er1   = (float*)(w + alloc((size_t)N * H1 * 4));
    unsigned short* h1b = (unsigned short*)(w + alloc((size_t)N * F1 * 2));
    unsigned short* feat2b = (unsigned short*)(w + alloc((size_t)N * F2 * 2));
    float* el2   = (float*)(w + alloc((size_t)N * H2 * 4));
    float* er2   = (float*)(w + alloc((size_t)N * H2 * 4));
    unsigned short* W1h = (unsigned short*)(w + alloc((size_t)F_IN * F1 * 2));
    unsigned short* W1l = (unsigned short*)(w + alloc((size_t)F_IN * F1 * 2));
    unsigned short* W2h = (unsigned short*)(w + alloc((size_t)F1 * F2 * 2));
    unsigned short* W2l = (unsigned short*)(w + alloc((size_t)F1 * F2 * 2));
    (void)ws_size; (void)n_in; (void)out_size;

    // ---- CSR build: bucketed counting sort (4 kernels, full grid width each) ----
    chist<<<CB, 256, 0, stream>>>(dst, HcT, E, NBUK);
    bscan<<<1, 512, 0, stream>>>(HcT, Bb, S, NBUK);
    cscat<<<CB, 256, 0, stream>>>(src, dst, Bb, S, pairs, E, NBUK);
    fscat<<<NBUK, 256, 0, stream>>>(pairs, S, off, csr, N, E);

    // ---- prep: weight split+swizzle and X swizzle, one launch ----
    prep_kernel<<<WBLK + (NROWP + 7) / 8, 256, 0, stream>>>(
        W1, W1h, W1l, W2, W2h, W2l, x, xb, N, NROWP);

    // ---- layer 1 ----
    gemm1_mfma<<<NBLK1, 256, 0, stream>>>(
        xb, W1h, W1l, al1, ar1, feat1b, el1, er1, N);
    agg1_kernel<<<(N + 3) / 4, 256, 0, stream>>>(off, csr, feat1b, el1, er1, b1, h1b, N);

    // ---- layer 2 ----
    gemm2_mfma<<<(N + BM2 - 1) / BM2, 256, 0, stream>>>(
        h1b, W2h, W2l, al2, ar2, feat2b, el2, er2, N);
    agg2_kernel<<<(N + 3) / 4, 256, 0, stream>>>(off, csr, feat2b, el2, er2, b2, (float*)d_out, N);
}